// Round 1
// baseline (59.110 us; speedup 1.0000x reference)
//
#include <hip/hip_runtime.h>
#include <hip/hip_bf16.h>
#include <math.h>

// Problem: B=64, C=3, H=W=512.
// out[b,0] = sigmoid( sum_{c,h,w} x[b,c,h,w] * M_col[h,w] / C )
// out[b,1] = sigmoid( sum_{c,h,w} x[b,c,h,w] * M_row[h,w] / C )
// M_row = (1/HW) Dh^T diag(rw) A Dw ;  M_col = (1/HW) Dh^T (A diag(cw)) Dw
// Dh == Dw == D (both dct_matrix(512)).

typedef __attribute__((ext_vector_type(8))) short bf16x8;   // 8 bf16 = 4 VGPRs
typedef __attribute__((ext_vector_type(4))) float f32x4;

#define NFULL 512
#define HWTOT 262144                    // 512*512
#define SCALE_M (1.0f / 786432.0f)      // 1/(H*W*C)

static __device__ __forceinline__ unsigned short f_to_bf16(float f) {
  union { float f; unsigned int i; } v; v.f = f;
  unsigned int r = v.i + 0x7FFFu + ((v.i >> 16) & 1u);   // round-nearest-even
  return (unsigned short)(r >> 16);
}

// ---------------- K0: trig table + bf16 casts ----------------
// DT[n][k] = s_k * cos(pi*(n+0.5)*k/512)  (this is D^T; D[k][n] row-major freq x spatial)
// Abf[k][l] = bf16(A[k,l]) ; Acw[k][l] = bf16(A[k,l]*cw[l])
__global__ void k0_prep(const float* __restrict__ att,
                        const float* __restrict__ cw,
                        unsigned short* __restrict__ DT,
                        unsigned short* __restrict__ Abf,
                        unsigned short* __restrict__ Acw) {
  int idx = blockIdx.x * blockDim.x + threadIdx.x;   // 0..262143
  int n = idx >> 9;
  int k = idx & 511;
  // exact integer phase reduction: cos(pi*(2n+1)*k/1024), period 2048
  unsigned int ph = ((unsigned int)(2 * n + 1) * (unsigned int)k) & 2047u;
  float s = (k == 0) ? 0.04419417382415922f   // sqrt(1/512)
                     : 0.0625f;               // sqrt(2/512) == 1/16
  float c = s * cospif((float)ph * (1.0f / 1024.0f));
  DT[idx] = f_to_bf16(c);
  float a = att[idx];
  Abf[idx] = f_to_bf16(a);
  Acw[idx] = f_to_bf16(a * cw[k]);
}

// ---------------- KA: G = A@Dw, Gc = (A.*cw)@Dw ; store transposed bf16 ----------------
// One wave computes one 16x16 tile of both outputs. B-operand (DT rows) shared.
// GrowT[w][k] = rw[k]*G[k][w] ; GcT[w][k] = Gc[k][w]
__global__ void ka_gemm(const unsigned short* __restrict__ DT,
                        const unsigned short* __restrict__ Abf,
                        const unsigned short* __restrict__ Acw,
                        const float* __restrict__ rw,
                        unsigned short* __restrict__ GrowT,
                        unsigned short* __restrict__ GcT) {
  int wave = (blockIdx.x * blockDim.x + threadIdx.x) >> 6;   // 0..1023
  int lane = threadIdx.x & 63;
  int tk = wave >> 5, tw = wave & 31;
  int row_a = tk * 16 + (lane & 15);     // k-row of A
  int row_b = tw * 16 + (lane & 15);     // w-row of DT (= output col)
  int koff = (lane >> 4) * 8;

  const bf16x8* Ap = (const bf16x8*)(Abf + row_a * NFULL);
  const bf16x8* Cp = (const bf16x8*)(Acw + row_a * NFULL);
  const bf16x8* Bp = (const bf16x8*)(DT  + row_b * NFULL);

  f32x4 accG = {0.f, 0.f, 0.f, 0.f};
  f32x4 accC = {0.f, 0.f, 0.f, 0.f};
#pragma unroll 4
  for (int l0 = 0; l0 < NFULL; l0 += 32) {
    int e = (l0 + koff) >> 3;
    bf16x8 a = Ap[e];
    bf16x8 c = Cp[e];
    bf16x8 b = Bp[e];
    accG = __builtin_amdgcn_mfma_f32_16x16x32_bf16(a, b, accG, 0, 0, 0);
    accC = __builtin_amdgcn_mfma_f32_16x16x32_bf16(c, b, accC, 0, 0, 0);
  }
  // C/D layout (HW-verified): col = lane&15, row = (lane>>4)*4 + j
  int col = lane & 15, r0 = (lane >> 4) * 4;
  int w  = tw * 16 + col;
  int k0 = tk * 16 + r0;
  unsigned int g0 = f_to_bf16(accG[0] * rw[k0 + 0]) | ((unsigned int)f_to_bf16(accG[1] * rw[k0 + 1]) << 16);
  unsigned int g1 = f_to_bf16(accG[2] * rw[k0 + 2]) | ((unsigned int)f_to_bf16(accG[3] * rw[k0 + 3]) << 16);
  unsigned int c0 = f_to_bf16(accC[0]) | ((unsigned int)f_to_bf16(accC[1]) << 16);
  unsigned int c1 = f_to_bf16(accC[2]) | ((unsigned int)f_to_bf16(accC[3]) << 16);
  uint2* pg = (uint2*)(GrowT + w * NFULL + k0);
  uint2* pc = (uint2*)(GcT   + w * NFULL + k0);
  *pg = make_uint2(g0, g1);
  *pc = make_uint2(c0, c1);
}

// ---------------- KB: M_row = Dh^T @ Grow, M_col = Dh^T @ Gc (fp32 out, scaled) ----------------
__global__ void kb_gemm(const unsigned short* __restrict__ DT,
                        const unsigned short* __restrict__ GrowT,
                        const unsigned short* __restrict__ GcT,
                        float* __restrict__ Mrow,
                        float* __restrict__ Mcol) {
  int wave = (blockIdx.x * blockDim.x + threadIdx.x) >> 6;
  int lane = threadIdx.x & 63;
  int th = wave >> 5, tw = wave & 31;
  int row_a = th * 16 + (lane & 15);     // h-row of Dh^T  (DhT[h][k] = DT[h][k])
  int row_b = tw * 16 + (lane & 15);     // w-row of G^T
  int koff = (lane >> 4) * 8;

  const bf16x8* Ap = (const bf16x8*)(DT    + row_a * NFULL);
  const bf16x8* Rp = (const bf16x8*)(GrowT + row_b * NFULL);
  const bf16x8* Cp = (const bf16x8*)(GcT   + row_b * NFULL);

  f32x4 accR = {0.f, 0.f, 0.f, 0.f};
  f32x4 accC = {0.f, 0.f, 0.f, 0.f};
#pragma unroll 4
  for (int k0 = 0; k0 < NFULL; k0 += 32) {
    int e = (k0 + koff) >> 3;
    bf16x8 a  = Ap[e];
    bf16x8 bR = Rp[e];
    bf16x8 bC = Cp[e];
    accR = __builtin_amdgcn_mfma_f32_16x16x32_bf16(a, bR, accR, 0, 0, 0);
    accC = __builtin_amdgcn_mfma_f32_16x16x32_bf16(a, bC, accC, 0, 0, 0);
  }
  int col = lane & 15, r0 = (lane >> 4) * 4;
  int h0 = th * 16 + r0;
  int w  = tw * 16 + col;
#pragma unroll
  for (int j = 0; j < 4; ++j) {
    Mrow[(h0 + j) * NFULL + w] = accR[j] * SCALE_M;
    Mcol[(h0 + j) * NFULL + w] = accC[j] * SCALE_M;
  }
}

// ---------------- KC: stream x, fused channel-sum + two dot products ----------------
#define NBLK 32   // blocks per batch image
__global__ void kc_dot(const float* __restrict__ x,
                       const float* __restrict__ Mcol,
                       const float* __restrict__ Mrow,
                       float* __restrict__ partial) {
  int b   = blockIdx.x >> 5;
  int sub = blockIdx.x & 31;
  int tid = threadIdx.x;
  const float4* xb = (const float4*)x + (size_t)b * 196608;   // 3*65536 float4
  const float4* mc = (const float4*)Mcol;
  const float4* mr = (const float4*)Mrow;

  float a0 = 0.f, a1 = 0.f;
  int base = sub * 2048 + tid;
#pragma unroll
  for (int it = 0; it < 8; ++it) {
    int i = base + it * 256;            // hw float4 index, 0..65535
    float4 x0 = xb[i];
    float4 x1 = xb[i + 65536];
    float4 x2 = xb[i + 131072];
    float4 m0 = mc[i];
    float4 m1 = mr[i];
    float sx = x0.x + x1.x + x2.x;
    float sy = x0.y + x1.y + x2.y;
    float sz = x0.z + x1.z + x2.z;
    float sw = x0.w + x1.w + x2.w;
    a0 += sx * m0.x + sy * m0.y + sz * m0.z + sw * m0.w;
    a1 += sx * m1.x + sy * m1.y + sz * m1.z + sw * m1.w;
  }
  __shared__ float s0[256];
  __shared__ float s1[256];
  s0[tid] = a0; s1[tid] = a1;
  __syncthreads();
#pragma unroll
  for (int off = 128; off > 0; off >>= 1) {
    if (tid < off) { s0[tid] += s0[tid + off]; s1[tid] += s1[tid + off]; }
    __syncthreads();
  }
  if (tid == 0) {
    partial[(b * NBLK + sub) * 2 + 0] = s0[0];
    partial[(b * NBLK + sub) * 2 + 1] = s1[0];
  }
}

// ---------------- KD: final deterministic reduce + sigmoid ----------------
__global__ void kd_final(const float* __restrict__ partial, float* __restrict__ out) {
  int t = threadIdx.x;           // 0..127 -> (b, o)
  int b = t >> 1, o = t & 1;
  float s = 0.f;
#pragma unroll
  for (int j = 0; j < NBLK; ++j) s += partial[(b * NBLK + j) * 2 + o];
  out[b * 2 + o] = 1.0f / (1.0f + expf(-s));
}

extern "C" void kernel_launch(void* const* d_in, const int* in_sizes, int n_in,
                              void* d_out, int out_size, void* d_ws, size_t ws_size,
                              hipStream_t stream) {
  const float* x   = (const float*)d_in[0];   // [64,3,512,512]
  const float* att = (const float*)d_in[1];   // [512,512]
  const float* rw  = (const float*)d_in[2];   // [512]
  const float* cw  = (const float*)d_in[3];   // [512]
  float* out = (float*)d_out;                 // [64,2]

  // workspace layout (needs ~4.6 MiB)
  unsigned short* DT    = (unsigned short*)d_ws;       // 512 KB bf16 D^T
  unsigned short* Abf   = DT    + HWTOT;               // 512 KB
  unsigned short* Acw   = Abf   + HWTOT;               // 512 KB
  unsigned short* GrowT = Acw   + HWTOT;               // 512 KB
  unsigned short* GcT   = GrowT + HWTOT;               // 512 KB
  float* Mrow    = (float*)(GcT + HWTOT);              // 1 MB
  float* Mcol    = Mrow + HWTOT;                       // 1 MB
  float* partial = Mcol + HWTOT;                       // 16 KB

  k0_prep<<<1024, 256, 0, stream>>>(att, cw, DT, Abf, Acw);
  ka_gemm<<<256, 256, 0, stream>>>(DT, Abf, Acw, rw, GrowT, GcT);
  kb_gemm<<<256, 256, 0, stream>>>(DT, GrowT, GcT, Mrow, Mcol);
  kc_dot<<<64 * NBLK, 256, 0, stream>>>(x, Mcol, Mrow, partial);
  kd_final<<<1, 128, 0, stream>>>(partial, out);
}